// Round 4
// baseline (189.059 us; speedup 1.0000x reference)
//
#include <hip/hip_runtime.h>

// ---------------------------------------------------------------------------
// ConvFeatureExtractor: profile = rownorm( freq @ softmax(matches/T, axis=1)^T )
//   matches[f,i] = sum_j kmer_params[f, digit_j(i), j],  F=8192, M=4096, B=1024, K=6
// R4: split-K=2 GEMM (grid 64x8x2 = 1024 blocks = 4 blocks/CU, the LDS cap) to
//     fix grid-limited occupancy (R3: 19.8% occ vs 25% grid cap, MfmaUtil 31%).
//     k-chunk 0 -> d_out, k-chunk 1 -> ws partial; norm_kernel fuses the add.
// ---------------------------------------------------------------------------

typedef __bf16  bf16x8 __attribute__((ext_vector_type(8)));
typedef float   f32x4  __attribute__((ext_vector_type(4)));
typedef short   short8v __attribute__((ext_vector_type(8)));

#define GLD16(gp, lp)                                                          \
  __builtin_amdgcn_global_load_lds(                                            \
      (const __attribute__((address_space(1))) void*)(gp),                     \
      (__attribute__((address_space(3))) void*)(lp), 16, 0, 0)

__device__ __forceinline__ short f2bf(float x) {
  unsigned u = __float_as_uint(x);
  unsigned r = (u + 0x7fffu + ((u >> 16) & 1u)) >> 16;   // RNE
  return (short)r;
}

__device__ __forceinline__ float wave_max(float v) {
  #pragma unroll
  for (int off = 32; off; off >>= 1) v = fmaxf(v, __shfl_xor(v, off, 64));
  return v;
}
__device__ __forceinline__ float wave_sum(float v) {
  #pragma unroll
  for (int off = 32; off; off >>= 1) v += __shfl_xor(v, off, 64);
  return v;
}

// ---------------- k1: freq f32 -> bf16 ----------------
__global__ __launch_bounds__(256) void cast_kernel(const float* __restrict__ in,
                                                   short* __restrict__ out) {
  int idx = blockIdx.x * 256 + threadIdx.x;      // 4 floats each
  float4 v = ((const float4*)in)[idx];
  short4 o;
  o.x = f2bf(v.x); o.y = f2bf(v.y); o.z = f2bf(v.z); o.w = f2bf(v.w);
  ((short4*)out)[idx] = o;
}

// ---------------- k2: matches + softmax -> probs bf16 ----------------
// grid = 8192 (one block per filter), block = 256; thread t owns kmers
// [t*16, t*16+16) which share a single Thi entry (t>>2).
__global__ __launch_bounds__(256) void probs_kernel(const float* __restrict__ kp,
                                                    const float* __restrict__ temp,
                                                    short* __restrict__ probs) {
  const int f = blockIdx.x;
  const int t = threadIdx.x;
  const int lane = t & 63, wave = t >> 6;

  __shared__ float P[24];          // kmer_params[f] : [4][6]
  __shared__ float Thi[64], Tlo[64];
  __shared__ float redA[4], redB[4];

  if (t < 24) P[t] = kp[f * 24 + t];
  __syncthreads();
  if (t < 64) {
    // digits most-significant first: Thi covers j=0,1,2 ; Tlo covers j=3,4,5
    Thi[t] = P[((t >> 4) & 3) * 6 + 0] + P[((t >> 2) & 3) * 6 + 1] + P[(t & 3) * 6 + 2];
    Tlo[t] = P[((t >> 4) & 3) * 6 + 3] + P[((t >> 2) & 3) * 6 + 4] + P[(t & 3) * 6 + 5];
  }
  __syncthreads();

  const float hi = Thi[t >> 2];
  const int lo0 = (t & 3) * 16;
  float m[16];
  float mx = -1e30f;
  #pragma unroll
  for (int s = 0; s < 16; s++) {
    m[s] = hi + Tlo[lo0 + s];
    mx = fmaxf(mx, m[s]);
  }
  float wmx = wave_max(mx);
  if (lane == 0) redA[wave] = wmx;
  __syncthreads();
  mx = fmaxf(fmaxf(redA[0], redA[1]), fmaxf(redA[2], redA[3]));

  const float invT = 1.0f / temp[0];
  float e[16];
  float lsum = 0.0f;
  #pragma unroll
  for (int s = 0; s < 16; s++) {
    e[s] = __expf((m[s] - mx) * invT);
    lsum += e[s];
  }
  float wsum = wave_sum(lsum);
  if (lane == 0) redB[wave] = wsum;
  __syncthreads();
  float tot = (redB[0] + redB[1]) + (redB[2] + redB[3]);
  float inv = 1.0f / tot;

  short8v* prow = (short8v*)(probs + (size_t)f * 4096 + t * 16);
  short8v o0, o1;
  #pragma unroll
  for (int s = 0; s < 8; s++) { o0[s] = f2bf(e[s] * inv); o1[s] = f2bf(e[s + 8] * inv); }
  prow[0] = o0;
  prow[1] = o1;
}

// ---------------- k3: GEMM pooled = A(1024x4096) * B(8192x4096)^T ----------------
// Split-K=2: blockIdx.z selects K range [kz*2048, kz*2048+2048) and the output
// buffer (kz=0 -> C0=d_out, kz=1 -> C1=ws partial). norm_kernel adds them.
// Tiles: TM=128, TN=128, BK=64; 4 waves in 2x2, each 64x64 via 4x4 mfma 16x16x32.
// LDS tiles XOR-swizzled (physical col-block p at row r holds logical p^(r&7)):
// row stride 128B == 32 banks, so unswizzled fragment reads all hit one bank group.
__global__ __launch_bounds__(256) void gemm_kernel(const short* __restrict__ A,
                                                   const short* __restrict__ Bm,
                                                   float* __restrict__ C0,
                                                   float* __restrict__ C1) {
  __shared__ short As[128 * 64];
  __shared__ short Bs[128 * 64];

  const int t = threadIdx.x;
  const int lane = t & 63, wave = t >> 6;
  const int quad = lane >> 4, l16 = lane & 15;
  const int m0 = blockIdx.y * 128;       // batch tile
  const int n0 = blockIdx.x * 128;       // filter tile
  const int kz = blockIdx.z;             // split-K chunk
  const int wm = (wave & 1) * 64, wn = (wave >> 1) * 64;

  f32x4 acc[4][4];
  #pragma unroll
  for (int i = 0; i < 4; i++)
    #pragma unroll
    for (int j = 0; j < 4; j++) acc[i][j] = (f32x4){0.f, 0.f, 0.f, 0.f};

  const int lane_row = lane >> 3;                      // 0..7 within chunk
  const int src_col = ((lane & 7) ^ lane_row) * 8;     // swizzled global col (shorts)
  const int sw = l16 & 7;                              // reader swizzle key (= row&7)

  for (int kt = 0; kt < 32; kt++) {
    const int kofs = kz * 2048 + kt * 64;
    __syncthreads();
    #pragma unroll
    for (int c = 0; c < 4; c++) {
      const int chunk = wave * 4 + c;                  // 0..15
      const int row = chunk * 8 + lane_row;            // 0..127
      GLD16(A  + (m0 + row) * 4096 + kofs + src_col, &As[chunk * 512 + lane * 8]);
      GLD16(Bm + (n0 + row) * 4096 + kofs + src_col, &Bs[chunk * 512 + lane * 8]);
    }
    __syncthreads();

    #pragma unroll
    for (int ks = 0; ks < 2; ks++) {
      const int pcol = ((ks * 4 + quad) ^ sw) * 8;     // physical col (shorts)
      bf16x8 a[4], b[4];
      #pragma unroll
      for (int i = 0; i < 4; i++)
        a[i] = *(const bf16x8*)&As[(wm + i * 16 + l16) * 64 + pcol];
      #pragma unroll
      for (int j = 0; j < 4; j++)
        b[j] = *(const bf16x8*)&Bs[(wn + j * 16 + l16) * 64 + pcol];
      #pragma unroll
      for (int i = 0; i < 4; i++)
        #pragma unroll
        for (int j = 0; j < 4; j++)
          acc[i][j] = __builtin_amdgcn_mfma_f32_16x16x32_bf16(a[i], b[j], acc[i][j], 0, 0, 0);
    }
  }

  // epilogue: C/D layout col=lane&15, row=quad*4+reg
  float* __restrict__ C = kz ? C1 : C0;
  #pragma unroll
  for (int i = 0; i < 4; i++) {
    #pragma unroll
    for (int r = 0; r < 4; r++) {
      const int brow = m0 + wm + i * 16 + quad * 4 + r;
      float* crow = C + brow * 8192 + n0 + wn + l16;
      #pragma unroll
      for (int j = 0; j < 4; j++) crow[j * 16] = acc[i][j][r];
    }
  }
}

// ---------------- k4: add split-K partial + row-normalize (1024 rows of 8192) --
__global__ __launch_bounds__(256) void norm_kernel(float* __restrict__ out,
                                                   const float* __restrict__ p1) {
  const int b = blockIdx.x;
  const int t = threadIdx.x;
  const int lane = t & 63, wave = t >> 6;
  __shared__ float red[4];

  float4* row  = (float4*)(out + (size_t)b * 8192);        // 2048 float4
  const float4* row1 = (const float4*)(p1 + (size_t)b * 8192);
  float4 v[8];
  float s = 0.0f;
  #pragma unroll
  for (int q = 0; q < 8; q++) {
    float4 a = row[q * 256 + t];
    float4 c = row1[q * 256 + t];
    v[q].x = a.x + c.x; v[q].y = a.y + c.y; v[q].z = a.z + c.z; v[q].w = a.w + c.w;
    s += (v[q].x + v[q].y) + (v[q].z + v[q].w);
  }
  float ws = wave_sum(s);
  if (lane == 0) red[wave] = ws;
  __syncthreads();
  float tot = (red[0] + red[1]) + (red[2] + red[3]);
  float inv = 1.0f / tot;
  #pragma unroll
  for (int q = 0; q < 8; q++) {
    v[q].x *= inv; v[q].y *= inv; v[q].z *= inv; v[q].w *= inv;
    row[q * 256 + t] = v[q];
  }
}

// ---------------------------------------------------------------------------
extern "C" void kernel_launch(void* const* d_in, const int* in_sizes, int n_in,
                              void* d_out, int out_size, void* d_ws, size_t ws_size,
                              hipStream_t stream) {
  const float* freq    = (const float*)d_in[0];   // 1024*4096
  const float* kparams = (const float*)d_in[1];   // 8192*4*6
  const float* temp    = (const float*)d_in[2];   // 1
  // d_in[3] = kmer_idcs (recomputed analytically in-kernel)

  float* out = (float*)d_out;                     // 1024*8192 f32

  short* probs = (short*)d_ws;                       // 8192*4096 bf16 = 64 MiB
  short* freqb = probs + (size_t)8192 * 4096;        // 1024*4096 bf16 =  8 MiB
  float* part1 = (float*)(freqb + (size_t)1024 * 4096); // 1024*8192 f32 = 32 MiB

  cast_kernel <<<4096, 256, 0, stream>>>(freq, freqb);
  probs_kernel<<<8192, 256, 0, stream>>>(kparams, temp, probs);
  gemm_kernel <<<dim3(64, 8, 2), 256, 0, stream>>>(freqb, probs, out, part1);
  norm_kernel <<<1024, 256, 0, stream>>>(out, part1);
}

// Round 5
// 164.951 us; speedup vs baseline: 1.1462x; 1.1462x over previous
//
#include <hip/hip_runtime.h>

// ---------------------------------------------------------------------------
// ConvFeatureExtractor: profile = rownorm( freq @ softmax(matches/T, axis=1)^T )
//   matches[f,i] = Thi[f, i>>6] + Tlo[f, i&63]  (separable!), F=8192, M=4096,
//   B=1024, K=6.  =>  probs[f,i] = e1[f,i>>6] * e2[f,i&63],  Z = (sum e1)(sum e2).
// R5: B is NEVER materialized. GEMM stages only A; B-fragments are built in
//     registers from e2 (preloaded per block) x e1[f,kt] (64 B/wave/iter).
//     Kills probs_kernel + 64MB write + 64MB read, halves staging traffic
//     (R4 evidence: extra blocks didn't help -> fabric-BW bound at ~11 TB/s).
// ---------------------------------------------------------------------------

typedef __bf16  bf16x8 __attribute__((ext_vector_type(8)));
typedef float   f32x4  __attribute__((ext_vector_type(4)));

#define GLD16(gp, lp)                                                          \
  __builtin_amdgcn_global_load_lds(                                            \
      (const __attribute__((address_space(1))) void*)(gp),                     \
      (__attribute__((address_space(3))) void*)(lp), 16, 0, 0)

__device__ __forceinline__ short f2bf(float x) {
  unsigned u = __float_as_uint(x);
  unsigned r = (u + 0x7fffu + ((u >> 16) & 1u)) >> 16;   // RNE
  return (short)r;
}

__device__ __forceinline__ float wave_max(float v) {
  #pragma unroll
  for (int off = 32; off; off >>= 1) v = fmaxf(v, __shfl_xor(v, off, 64));
  return v;
}
__device__ __forceinline__ float wave_sum(float v) {
  #pragma unroll
  for (int off = 32; off; off >>= 1) v += __shfl_xor(v, off, 64);
  return v;
}

// ---------------- k1: freq f32 -> bf16 ----------------
__global__ __launch_bounds__(256) void cast_kernel(const float* __restrict__ in,
                                                   short* __restrict__ out) {
  int idx = blockIdx.x * 256 + threadIdx.x;      // 4 floats each
  float4 v = ((const float4*)in)[idx];
  short4 o;
  o.x = f2bf(v.x); o.y = f2bf(v.y); o.z = f2bf(v.z); o.w = f2bf(v.w);
  ((short4*)out)[idx] = o;
}

// ---------------- k2: softmax factor tables ----------------
// One wave per filter (4 filters/block). lane l:
//   Thi_l = P[d0*6+0]+P[d1*6+1]+P[d2*6+2], Tlo_l = P[d0*6+3]+P[d1*6+4]+P[d2*6+5]
// e1 = exp((Thi-mxhi)/T), e2 = exp((Tlo-mxlo)/T), Z = (sum e1)(sum e2).
// E1t[l][f] (transposed, f32, 1/Z folded in) for coalesced GEMM reads;
// E2[f][l] (f32).
__global__ __launch_bounds__(256) void tables_kernel(const float* __restrict__ kp,
                                                     const float* __restrict__ temp,
                                                     float* __restrict__ E1t,
                                                     float* __restrict__ E2) {
  const int t = threadIdx.x;
  const int lane = t & 63, wave = t >> 6;
  const int f = blockIdx.x * 4 + wave;
  const float* P = kp + f * 24;
  const int d0 = (lane >> 4) & 3, d1 = (lane >> 2) & 3, d2 = lane & 3;
  const float thi = P[d0 * 6 + 0] + P[d1 * 6 + 1] + P[d2 * 6 + 2];
  const float tlo = P[d0 * 6 + 3] + P[d1 * 6 + 4] + P[d2 * 6 + 5];
  const float mxhi = wave_max(thi), mxlo = wave_max(tlo);
  const float invT = 1.0f / temp[0];
  const float e1 = __expf((thi - mxhi) * invT);
  const float e2 = __expf((tlo - mxlo) * invT);
  const float s1 = wave_sum(e1), s2 = wave_sum(e2);
  const float invZ = 1.0f / (s1 * s2);
  E1t[lane * 8192 + f] = e1 * invZ;
  E2[(size_t)f * 64 + lane] = e2;
}

// ---------------- k3: GEMM pooled = A(1024x4096) * B^T, B[f,i]=e1[f,i>>6]e2[f,i&63]
// Tiles: TM=128, TN=128, BK=64; 4 waves 2x2, each 64x64 via 4x4 mfma 16x16x32.
// Only A staged in LDS (XOR-swizzled: row stride 128B == 32 banks otherwise).
// B-fragments: e2 frags (f32) preloaded once per block; per kt multiply by
// e1[f,kt] (coalesced 64B/wave read from E1t) and convert to bf16 in regs.
__global__ __launch_bounds__(256, 2) void gemm_kernel(const short* __restrict__ A,
                                                      const float* __restrict__ E1t,
                                                      const float* __restrict__ E2,
                                                      float* __restrict__ C) {
  __shared__ short As[128 * 64];

  const int t = threadIdx.x;
  const int lane = t & 63, wave = t >> 6;
  const int quad = lane >> 4, l16 = lane & 15;
  const int m0 = blockIdx.y * 128;       // batch tile
  const int n0 = blockIdx.x * 128;       // filter tile
  const int wm = (wave & 1) * 64, wn = (wave >> 1) * 64;

  f32x4 acc[4][4];
  #pragma unroll
  for (int i = 0; i < 4; i++)
    #pragma unroll
    for (int j = 0; j < 4; j++) acc[i][j] = (f32x4){0.f, 0.f, 0.f, 0.f};

  // preload e2 fragments (f32): lane (l16,quad) of frag (j,ks) covers
  // k-in-slice = (ks*4+quad)*8 + 0..7 for filter row nrow[j]
  int nrow[4];
  #pragma unroll
  for (int j = 0; j < 4; j++) nrow[j] = n0 + wn + j * 16 + l16;
  float4 e2a[4][2], e2b[4][2];
  #pragma unroll
  for (int j = 0; j < 4; j++)
    #pragma unroll
    for (int ks = 0; ks < 2; ks++) {
      const float* p = E2 + (size_t)nrow[j] * 64 + (ks * 4 + quad) * 8;
      e2a[j][ks] = *(const float4*)p;
      e2b[j][ks] = *(const float4*)(p + 4);
    }

  const int lane_row = lane >> 3;                      // 0..7 within chunk
  const int src_col = ((lane & 7) ^ lane_row) * 8;     // swizzled global col (shorts)
  const int sw = l16 & 7;                              // reader swizzle key (= row&7)

  for (int kt = 0; kt < 64; kt++) {
    const int kofs = kt * 64;
    float e1v[4];
    #pragma unroll
    for (int j = 0; j < 4; j++) e1v[j] = E1t[kt * 8192 + nrow[j]];

    __syncthreads();
    #pragma unroll
    for (int c = 0; c < 4; c++) {
      const int chunk = wave * 4 + c;                  // 0..15
      const int row = chunk * 8 + lane_row;            // 0..127
      GLD16(A + (m0 + row) * 4096 + kofs + src_col, &As[chunk * 512 + lane * 8]);
    }
    __syncthreads();

    // build B fragments in registers: b = bf16(e1 * e2)
    bf16x8 b[2][4];
    #pragma unroll
    for (int j = 0; j < 4; j++)
      #pragma unroll
      for (int ks = 0; ks < 2; ks++) {
        const float s = e1v[j];
        bf16x8 bb;
        bb[0] = (__bf16)(s * e2a[j][ks].x);
        bb[1] = (__bf16)(s * e2a[j][ks].y);
        bb[2] = (__bf16)(s * e2a[j][ks].z);
        bb[3] = (__bf16)(s * e2a[j][ks].w);
        bb[4] = (__bf16)(s * e2b[j][ks].x);
        bb[5] = (__bf16)(s * e2b[j][ks].y);
        bb[6] = (__bf16)(s * e2b[j][ks].z);
        bb[7] = (__bf16)(s * e2b[j][ks].w);
        b[ks][j] = bb;
      }

    #pragma unroll
    for (int ks = 0; ks < 2; ks++) {
      const int pcol = ((ks * 4 + quad) ^ sw) * 8;     // physical col (shorts)
      bf16x8 a[4];
      #pragma unroll
      for (int i = 0; i < 4; i++)
        a[i] = *(const bf16x8*)&As[(wm + i * 16 + l16) * 64 + pcol];
      #pragma unroll
      for (int i = 0; i < 4; i++)
        #pragma unroll
        for (int j = 0; j < 4; j++)
          acc[i][j] = __builtin_amdgcn_mfma_f32_16x16x32_bf16(a[i], b[ks][j], acc[i][j], 0, 0, 0);
    }
  }

  // epilogue: C/D layout col=lane&15, row=quad*4+reg
  #pragma unroll
  for (int i = 0; i < 4; i++) {
    #pragma unroll
    for (int r = 0; r < 4; r++) {
      const int brow = m0 + wm + i * 16 + quad * 4 + r;
      float* crow = C + (size_t)brow * 8192 + n0 + wn + l16;
      #pragma unroll
      for (int j = 0; j < 4; j++) crow[j * 16] = acc[i][j][r];
    }
  }
}

// ---------------- k4: row-normalize d_out (1024 rows of 8192) ----------------
__global__ __launch_bounds__(256) void norm_kernel(float* __restrict__ out) {
  const int b = blockIdx.x;
  const int t = threadIdx.x;
  const int lane = t & 63, wave = t >> 6;
  __shared__ float red[4];

  float4* row = (float4*)(out + (size_t)b * 8192);   // 2048 float4
  float4 v[8];
  float s = 0.0f;
  #pragma unroll
  for (int q = 0; q < 8; q++) {
    v[q] = row[q * 256 + t];
    s += (v[q].x + v[q].y) + (v[q].z + v[q].w);
  }
  float ws = wave_sum(s);
  if (lane == 0) red[wave] = ws;
  __syncthreads();
  float tot = (red[0] + red[1]) + (red[2] + red[3]);
  float inv = 1.0f / tot;
  #pragma unroll
  for (int q = 0; q < 8; q++) {
    v[q].x *= inv; v[q].y *= inv; v[q].z *= inv; v[q].w *= inv;
    row[q * 256 + t] = v[q];
  }
}

// ---------------------------------------------------------------------------
extern "C" void kernel_launch(void* const* d_in, const int* in_sizes, int n_in,
                              void* d_out, int out_size, void* d_ws, size_t ws_size,
                              hipStream_t stream) {
  const float* freq    = (const float*)d_in[0];   // 1024*4096
  const float* kparams = (const float*)d_in[1];   // 8192*4*6
  const float* temp    = (const float*)d_in[2];   // 1
  // d_in[3] = kmer_idcs (recomputed analytically in-kernel)

  float* out = (float*)d_out;                     // 1024*8192 f32

  short* freqb = (short*)d_ws;                    // 1024*4096 bf16 = 8 MiB
  float* E1t   = (float*)(freqb + (size_t)1024 * 4096);  // 64*8192 f32 = 2 MiB
  float* E2    = E1t + (size_t)64 * 8192;                // 8192*64 f32 = 2 MiB

  cast_kernel  <<<4096, 256, 0, stream>>>(freq, freqb);
  tables_kernel<<<2048, 256, 0, stream>>>(kparams, temp, E1t, E2);
  gemm_kernel  <<<dim3(64, 8), 256, 0, stream>>>(freqb, E1t, E2, out);
  norm_kernel  <<<1024, 256, 0, stream>>>(out);
}

// Round 6
// 162.081 us; speedup vs baseline: 1.1665x; 1.0177x over previous
//
#include <hip/hip_runtime.h>

// ---------------------------------------------------------------------------
// ConvFeatureExtractor: profile = rownorm( freq @ softmax(matches/T, axis=1)^T )
//   matches[f,i] = Thi[f, i>>6] + Tlo[f, i&63]  (separable!), F=8192, M=4096,
//   B=1024, K=6.  =>  probs[f,i] = e1[f,i>>6] * e2[f,i&63],  Z = (sum e1)(sum e2).
// R6: occupancy fix. R5 was latency-bound (real MFMA busy ~10%, fabric 6.5 of
//     ~11 TB/s, 2 blocks/CU grid-limited). TM=64 x TN=128 -> 1024 blocks =
//     4 blocks/CU, 16 waves/CU; A traffic unchanged (no B staging exists).
// ---------------------------------------------------------------------------

typedef __bf16  bf16x8 __attribute__((ext_vector_type(8)));
typedef float   f32x4  __attribute__((ext_vector_type(4)));

#define GLD16(gp, lp)                                                          \
  __builtin_amdgcn_global_load_lds(                                            \
      (const __attribute__((address_space(1))) void*)(gp),                     \
      (__attribute__((address_space(3))) void*)(lp), 16, 0, 0)

__device__ __forceinline__ short f2bf(float x) {
  unsigned u = __float_as_uint(x);
  unsigned r = (u + 0x7fffu + ((u >> 16) & 1u)) >> 16;   // RNE
  return (short)r;
}

__device__ __forceinline__ float wave_max(float v) {
  #pragma unroll
  for (int off = 32; off; off >>= 1) v = fmaxf(v, __shfl_xor(v, off, 64));
  return v;
}
__device__ __forceinline__ float wave_sum(float v) {
  #pragma unroll
  for (int off = 32; off; off >>= 1) v += __shfl_xor(v, off, 64);
  return v;
}

// ---------------- k1: freq f32 -> bf16 ----------------
__global__ __launch_bounds__(256) void cast_kernel(const float* __restrict__ in,
                                                   short* __restrict__ out) {
  int idx = blockIdx.x * 256 + threadIdx.x;      // 4 floats each
  float4 v = ((const float4*)in)[idx];
  short4 o;
  o.x = f2bf(v.x); o.y = f2bf(v.y); o.z = f2bf(v.z); o.w = f2bf(v.w);
  ((short4*)out)[idx] = o;
}

// ---------------- k2: softmax factor tables ----------------
// One wave per filter (4 filters/block). lane l:
//   Thi_l = P[d0*6+0]+P[d1*6+1]+P[d2*6+2], Tlo_l = P[d0*6+3]+P[d1*6+4]+P[d2*6+5]
// e1 = exp((Thi-mxhi)/T), e2 = exp((Tlo-mxlo)/T), Z = (sum e1)(sum e2).
// E1t[l][f] (transposed, f32, 1/Z folded in) for coalesced GEMM reads;
// E2[f][l] (f32).
__global__ __launch_bounds__(256) void tables_kernel(const float* __restrict__ kp,
                                                     const float* __restrict__ temp,
                                                     float* __restrict__ E1t,
                                                     float* __restrict__ E2) {
  const int t = threadIdx.x;
  const int lane = t & 63, wave = t >> 6;
  const int f = blockIdx.x * 4 + wave;
  const float* P = kp + f * 24;
  const int d0 = (lane >> 4) & 3, d1 = (lane >> 2) & 3, d2 = lane & 3;
  const float thi = P[d0 * 6 + 0] + P[d1 * 6 + 1] + P[d2 * 6 + 2];
  const float tlo = P[d0 * 6 + 3] + P[d1 * 6 + 4] + P[d2 * 6 + 5];
  const float mxhi = wave_max(thi), mxlo = wave_max(tlo);
  const float invT = 1.0f / temp[0];
  const float e1 = __expf((thi - mxhi) * invT);
  const float e2 = __expf((tlo - mxlo) * invT);
  const float s1 = wave_sum(e1), s2 = wave_sum(e2);
  const float invZ = 1.0f / (s1 * s2);
  E1t[lane * 8192 + f] = e1 * invZ;
  E2[(size_t)f * 64 + lane] = e2;
}

// ---------------- k3: GEMM pooled = A(1024x4096) * B^T, B[f,i]=e1[f,i>>6]e2[f,i&63]
// Tiles: TM=64, TN=128, BK=64; grid 64x16 = 1024 blocks (4/CU, 16 waves/CU).
// 4 waves side-by-side in N: wave tile 64(m) x 32(n) = 4x2 frags of 16x16x32.
// Only A staged in LDS (XOR-swizzled: row stride 128B == 32 banks otherwise).
// B-fragments built in regs: e2 frags (f32) preloaded once; per kt scale by
// e1[f,kt] (coalesced read from E1t) and convert to bf16.
__global__ __launch_bounds__(256, 4) void gemm_kernel(const short* __restrict__ A,
                                                      const float* __restrict__ E1t,
                                                      const float* __restrict__ E2,
                                                      float* __restrict__ C) {
  __shared__ short As[64 * 64];

  const int t = threadIdx.x;
  const int lane = t & 63, wave = t >> 6;
  const int quad = lane >> 4, l16 = lane & 15;
  const int m0 = blockIdx.y * 64;        // batch tile
  const int n0 = blockIdx.x * 128;       // filter tile
  const int wn = wave * 32;              // wave's n-offset within tile

  f32x4 acc[4][2];
  #pragma unroll
  for (int i = 0; i < 4; i++)
    #pragma unroll
    for (int j = 0; j < 2; j++) acc[i][j] = (f32x4){0.f, 0.f, 0.f, 0.f};

  // preload e2 fragments (f32): lane (l16,quad) of frag (j,ks) covers
  // k-in-slice = (ks*4+quad)*8 + 0..7 for filter row nrow[j]
  int nrow[2];
  #pragma unroll
  for (int j = 0; j < 2; j++) nrow[j] = n0 + wn + j * 16 + l16;
  float4 e2a[2][2], e2b[2][2];
  #pragma unroll
  for (int j = 0; j < 2; j++)
    #pragma unroll
    for (int ks = 0; ks < 2; ks++) {
      const float* p = E2 + (size_t)nrow[j] * 64 + (ks * 4 + quad) * 8;
      e2a[j][ks] = *(const float4*)p;
      e2b[j][ks] = *(const float4*)(p + 4);
    }

  const int lane_row = lane >> 3;                      // 0..7 within chunk
  const int src_col = ((lane & 7) ^ lane_row) * 8;     // swizzled global col (shorts)
  const int sw = l16 & 7;                              // reader swizzle key (= row&7)

  for (int kt = 0; kt < 64; kt++) {
    const int kofs = kt * 64;
    float e1v[2];
    #pragma unroll
    for (int j = 0; j < 2; j++) e1v[j] = E1t[kt * 8192 + nrow[j]];

    __syncthreads();
    #pragma unroll
    for (int c = 0; c < 2; c++) {
      const int chunk = wave * 2 + c;                  // 0..7
      const int row = chunk * 8 + lane_row;            // 0..63
      GLD16(A + (m0 + row) * 4096 + kofs + src_col, &As[chunk * 512 + lane * 8]);
    }
    __syncthreads();

    // build B fragments in registers: b = bf16(e1 * e2)
    bf16x8 b[2][2];
    #pragma unroll
    for (int j = 0; j < 2; j++)
      #pragma unroll
      for (int ks = 0; ks < 2; ks++) {
        const float s = e1v[j];
        bf16x8 bb;
        bb[0] = (__bf16)(s * e2a[j][ks].x);
        bb[1] = (__bf16)(s * e2a[j][ks].y);
        bb[2] = (__bf16)(s * e2a[j][ks].z);
        bb[3] = (__bf16)(s * e2a[j][ks].w);
        bb[4] = (__bf16)(s * e2b[j][ks].x);
        bb[5] = (__bf16)(s * e2b[j][ks].y);
        bb[6] = (__bf16)(s * e2b[j][ks].z);
        bb[7] = (__bf16)(s * e2b[j][ks].w);
        b[ks][j] = bb;
      }

    #pragma unroll
    for (int ks = 0; ks < 2; ks++) {
      const int pcol = ((ks * 4 + quad) ^ sw) * 8;     // physical col (shorts)
      bf16x8 a[4];
      #pragma unroll
      for (int i = 0; i < 4; i++)
        a[i] = *(const bf16x8*)&As[(i * 16 + l16) * 64 + pcol];
      #pragma unroll
      for (int i = 0; i < 4; i++)
        #pragma unroll
        for (int j = 0; j < 2; j++)
          acc[i][j] = __builtin_amdgcn_mfma_f32_16x16x32_bf16(a[i], b[ks][j], acc[i][j], 0, 0, 0);
    }
  }

  // epilogue: C/D layout col=lane&15, row=quad*4+reg
  #pragma unroll
  for (int i = 0; i < 4; i++) {
    #pragma unroll
    for (int r = 0; r < 4; r++) {
      const int brow = m0 + i * 16 + quad * 4 + r;
      float* crow = C + (size_t)brow * 8192 + n0 + wn + l16;
      #pragma unroll
      for (int j = 0; j < 2; j++) crow[j * 16] = acc[i][j][r];
    }
  }
}

// ---------------- k4: row-normalize d_out (1024 rows of 8192) ----------------
__global__ __launch_bounds__(256) void norm_kernel(float* __restrict__ out) {
  const int b = blockIdx.x;
  const int t = threadIdx.x;
  const int lane = t & 63, wave = t >> 6;
  __shared__ float red[4];

  float4* row = (float4*)(out + (size_t)b * 8192);   // 2048 float4
  float4 v[8];
  float s = 0.0f;
  #pragma unroll
  for (int q = 0; q < 8; q++) {
    v[q] = row[q * 256 + t];
    s += (v[q].x + v[q].y) + (v[q].z + v[q].w);
  }
  float ws = wave_sum(s);
  if (lane == 0) red[wave] = ws;
  __syncthreads();
  float tot = (red[0] + red[1]) + (red[2] + red[3]);
  float inv = 1.0f / tot;
  #pragma unroll
  for (int q = 0; q < 8; q++) {
    v[q].x *= inv; v[q].y *= inv; v[q].z *= inv; v[q].w *= inv;
    row[q * 256 + t] = v[q];
  }
}

// ---------------------------------------------------------------------------
extern "C" void kernel_launch(void* const* d_in, const int* in_sizes, int n_in,
                              void* d_out, int out_size, void* d_ws, size_t ws_size,
                              hipStream_t stream) {
  const float* freq    = (const float*)d_in[0];   // 1024*4096
  const float* kparams = (const float*)d_in[1];   // 8192*4*6
  const float* temp    = (const float*)d_in[2];   // 1
  // d_in[3] = kmer_idcs (recomputed analytically in-kernel)

  float* out = (float*)d_out;                     // 1024*8192 f32

  short* freqb = (short*)d_ws;                    // 1024*4096 bf16 = 8 MiB
  float* E1t   = (float*)(freqb + (size_t)1024 * 4096);  // 64*8192 f32 = 2 MiB
  float* E2    = E1t + (size_t)64 * 8192;                // 8192*64 f32 = 2 MiB

  cast_kernel  <<<4096, 256, 0, stream>>>(freq, freqb);
  tables_kernel<<<2048, 256, 0, stream>>>(kparams, temp, E1t, E2);
  gemm_kernel  <<<dim3(64, 16), 256, 0, stream>>>(freqb, E1t, E2, out);
  norm_kernel  <<<1024, 256, 0, stream>>>(out);
}